// Round 9
// baseline (392.338 us; speedup 1.0000x reference)
//
#include <hip/hip_runtime.h>
#include <math.h>

typedef unsigned short ushort_t;
typedef __attribute__((ext_vector_type(8))) _Float16 f16x8;
typedef __attribute__((ext_vector_type(4))) float f32x4;

// ---------- helpers ----------

__device__ inline unsigned fenc(float f) {
    unsigned u = __float_as_uint(f);
    return (u & 0x80000000u) ? ~u : (u | 0x80000000u);
}
__device__ inline float fdec(unsigned u) {
    return __uint_as_float((u & 0x80000000u) ? (u ^ 0x80000000u) : ~u);
}

__device__ inline float wrsum(float v) {
    #pragma unroll
    for (int m = 32; m; m >>= 1) v += __shfl_xor(v, m, 64);
    return v;
}
__device__ inline float lrelu(float x) { return x > 0.f ? x : 0.2f * x; }

__device__ inline ushort_t f2h(float f) {
    _Float16 h = (_Float16)f;              // RNE
    union { _Float16 h; ushort_t u; } cv;
    cv.h = h;
    return cv.u;
}

// acc += f16(lo half of pk) * w   /   acc += f16(hi half of pk) * w
#define FMAMIX_LO(acc, pk, w) \
    asm("v_fma_mix_f32 %0, %1, %2, %0 op_sel:[0,0,0] op_sel_hi:[1,0,0]" \
        : "+v"(acc) : "v"(pk), "v"(w))
#define FMAMIX_HI(acc, pk, w) \
    asm("v_fma_mix_f32 %0, %1, %2, %0 op_sel:[1,0,0] op_sel_hi:[1,0,0]" \
        : "+v"(acc) : "v"(pk), "v"(w))

// ---------- pre kernel: W swizzles + vab + inits ----------
__global__ __launch_bounds__(256) void pre_kernel(const float* __restrict__ W1,
                                                  const float* __restrict__ W2,
                                                  const float* __restrict__ a_src2,
                                                  const float* __restrict__ a_dst2,
                                                  ushort_t* __restrict__ W1s,
                                                  ushort_t* __restrict__ W2s,
                                                  float* __restrict__ va,
                                                  float* __restrict__ vb,
                                                  unsigned* __restrict__ minenc,
                                                  int* __restrict__ gtot) {
    int bid = blockIdx.x;
    int tid = threadIdx.x;
    if (bid < 128) {                       // W1 swizzle: 32768 elems
        int idx = bid * 256 + tid;
        int j = idx & 7;
        int lane = (idx >> 3) & 63;
        int ct = (idx >> 9) & 15;
        int kc = (idx >> 13) & 3;
        int k = kc * 32 + (lane >> 4) * 8 + j;
        int c = ct * 16 + (lane & 15);
        W1s[idx] = f2h(W1[k * 256 + c]);
    } else if (bid < 192) {                // W2 swizzle: 16384 elems
        int idx = (bid - 128) * 256 + tid;
        int j = idx & 7;
        int lane = (idx >> 3) & 63;
        int ct = (idx >> 9) & 3;
        int kc = idx >> 11;
        int k = kc * 32 + (lane >> 4) * 8 + j;
        int c = ct * 16 + (lane & 15);
        W2s[idx] = f2h(W2[k * 64 + c]);
    } else {                               // vab + minenc/gtot init
        int k = tid;
        float sa = 0.f, sb = 0.f;
        #pragma unroll 8
        for (int c = 0; c < 64; c++) {
            float w = W2[k * 64 + c];
            sa += w * a_src2[c];
            sb += w * a_dst2[c];
        }
        va[k] = sa;
        vb[k] = sb;
        if (tid < 64) minenc[tid] = 0xFFFFFFFFu;
        gtot[tid] = 0;
    }
}

// ---------- front kernel: MFMA gemm1 (f16) + scores1, with hist blocks appended ----------
// h1b is written in XCD-SLICED layout: slice k (channels [32k,32k+32)) is a
// contiguous N*64B region: addr(n,c) = (c>>5)*N*32 + n*32 + (c&31)  [ushorts]
__global__ __launch_bounds__(256) void front_kernel(const float* __restrict__ x,
                                                    const ushort_t* __restrict__ W1s,
                                                    const float* __restrict__ a_src,
                                                    const float* __restrict__ a_dst,
                                                    ushort_t* __restrict__ h1b,
                                                    float* __restrict__ ssrc,
                                                    float* __restrict__ sdst,
                                                    const int* __restrict__ ei,
                                                    int* __restrict__ bh,
                                                    int* __restrict__ gtot,
                                                    int N, int E, int Etot,
                                                    int nb16, int NBA, int BB) {
    __shared__ float ss[16 * 257];         // aliased: x staging first, D-tile after
    __shared__ float ps[256];
    int bid = blockIdx.x;
    int tid = threadIdx.x;

    if (bid >= nb16) {                     // ---- hist ----
        int* h = (int*)ps;
        int blk = bid - nb16;
        h[tid] = 0;
        __syncthreads();
        int i0 = blk * 4096 + tid;
        #pragma unroll
        for (int e = 0; e < 16; e++) {
            int i = i0 + e * 256;
            if (i < Etot) {
                int d = (i < E) ? ei[E + i] : (i - E);
                atomicAdd(&h[d >> 8], 1);
            }
        }
        __syncthreads();
        if (tid < BB) {
            bh[tid * NBA + blk] = h[tid];
            atomicAdd(&gtot[tid], h[tid]);
        }
        return;
    }

    // ---- stage x tile into LDS (coalesced; rows padded to 33 float4 = 132 floats) ----
    int base = bid * 16;
    {
        const float4* xv = (const float4*)(x + (size_t)base * 128);
        float4* xs4 = (float4*)ss;
        #pragma unroll
        for (int i = tid; i < 512; i += 256) {
            int row = i >> 5;              // 32 float4 per row
            float4 v = (base + row < N) ? xv[i] : make_float4(0.f, 0.f, 0.f, 0.f);
            xs4[row * 33 + (i & 31)] = v;
        }
    }
    __syncthreads();

    // ---- build A-fragments from LDS ----
    int lane = tid & 63, wv = tid >> 6;
    int m = lane & 15, q = lane >> 4;
    f16x8 afrag[4];
    #pragma unroll
    for (int kc = 0; kc < 4; kc++) {
        const float* xp = ss + m * 132 + kc * 32 + q * 8;
        float4 xa = *(const float4*)xp;
        float4 xb = *(const float4*)(xp + 4);
        f16x8 af;
        af[0] = (_Float16)xa.x; af[1] = (_Float16)xa.y;
        af[2] = (_Float16)xa.z; af[3] = (_Float16)xa.w;
        af[4] = (_Float16)xb.x; af[5] = (_Float16)xb.y;
        af[6] = (_Float16)xb.z; af[7] = (_Float16)xb.w;
        afrag[kc] = af;
    }
    __syncthreads();                       // xs dead; ss reused for D-tiles

    #pragma unroll
    for (int t = 0; t < 4; t++) {
        int ct = wv * 4 + t;
        f32x4 acc = {0.f, 0.f, 0.f, 0.f};
        #pragma unroll
        for (int kc = 0; kc < 4; kc++) {
            f16x8 bfrag = *(const f16x8*)(W1s + (((size_t)(kc * 16 + ct) * 64 + lane) << 3));
            acc = __builtin_amdgcn_mfma_f32_16x16x32_f16(afrag[kc], bfrag, acc, 0, 0, 0);
        }
        #pragma unroll
        for (int reg = 0; reg < 4; reg++) {
            ss[(q * 4 + reg) * 257 + ct * 16 + m] = acc[reg];
        }
    }
    __syncthreads();

    // ---- h1b writes, SLICED layout: thread (j, dd) packs channels dd*4..dd*4+3 ----
    int dd = tid & 63, jj = tid >> 6;
    #pragma unroll
    for (int t2 = 0; t2 < 4; t2++) {
        int j = jj + t2 * 4;
        int n = base + j;
        if (n < N) {
            const float* row = ss + j * 257 + dd * 4;
            unsigned p0 = (unsigned)f2h(row[0]) | ((unsigned)f2h(row[1]) << 16);
            unsigned p1 = (unsigned)f2h(row[2]) | ((unsigned)f2h(row[3]) << 16);
            *(uint2*)(h1b + (size_t)(dd >> 3) * N * 32 + (size_t)n * 32 + (dd & 7) * 4)
                = make_uint2(p0, p1);
        }
    }
    // ---- scores via partial sums (hh2-rotated) ----
    int j = tid & 15, hh2 = (tid >> 4) & 3, which = (tid >> 6) & 1, half = tid >> 7;
    const float* av = which ? a_dst : a_src;
    int cbase = hh2 * 64 + half * 32;
    float sum = 0.f;
    #pragma unroll
    for (int i = 0; i < 32; i++) {
        int ii = (i + 8 * hh2) & 31;
        sum += ss[j * 257 + cbase + ii] * av[cbase + ii];
    }
    ps[tid] = sum;
    __syncthreads();
    if (half == 0) {
        float tot = sum + ps[tid + 128];
        int n = base + j;
        if (n < N) (which ? sdst : ssrc)[n * 4 + hh2] = tot;
    }
}

// ---------- scan2: blocks 0..BB-1 scan bh rows over chunks; block BB scans gtot ----------
__global__ __launch_bounds__(256) void scan2_kernel(int* __restrict__ bh,
                                                    const int* __restrict__ gtot,
                                                    int* __restrict__ bstart,
                                                    int NBA, int BB) {
    __shared__ int sm[256];
    int b = blockIdx.x, t = threadIdx.x;
    if (b < BB) {                          // per-bucket exclusive scan over blocks
        int v = (t < NBA) ? bh[b * NBA + t] : 0;
        sm[t] = v;
        __syncthreads();
        for (int o = 1; o < 256; o <<= 1) {
            int a = (t >= o) ? sm[t - o] : 0;
            __syncthreads();
            sm[t] += a;
            __syncthreads();
        }
        if (t < NBA) bh[b * NBA + t] = sm[t] - v;
    } else {                               // bucket-level exclusive scan
        int v = (t < BB) ? gtot[t] : 0;
        sm[t] = v;
        __syncthreads();
        for (int o = 1; o < 256; o <<= 1) {
            int a = (t >= o) ? sm[t - o] : 0;
            __syncthreads();
            sm[t] += a;
            __syncthreads();
        }
        if (t < BB) bstart[t] = sm[t] - v;
        if (t == BB - 1) bstart[BB] = sm[t];
    }
}

// ---------- scat: recompute local ranks, block-local counting sort, run-coalesced writes ----------
__global__ __launch_bounds__(256) void scat_kernel(const int* __restrict__ ei,
                                                   const int* __restrict__ bh,
                                                   const int* __restrict__ bstart,
                                                   int* __restrict__ srcbuf,
                                                   int E, int Etot, int NBA, int BB) {
    __shared__ int h[256];
    __shared__ int loff[256];
    __shared__ int gb[256];
    __shared__ int su[4096];
    __shared__ int sp[4096];
    int t = threadIdx.x, blk = blockIdx.x;
    h[t] = 0;
    __syncthreads();
    int i0 = blk * 4096;
    int blkcnt = min(4096, Etot - i0);

    // pass 1: (bucket, rank) per edge via LDS atomics (counts match hist deterministically)
    int rb[16];
    #pragma unroll
    for (int e = 0; e < 16; e++) {
        int i = i0 + e * 256 + t;
        rb[e] = -1;
        if (i < Etot) {
            int d = (i < E) ? ei[E + i] : (i - E);
            int b = d >> 8;
            int r = atomicAdd(&h[b], 1);
            rb[e] = (b << 12) | r;         // r < 4096
        }
    }
    __syncthreads();

    // local exclusive offsets + global bases
    loff[t] = h[t];
    gb[t] = (t < BB) ? (bstart[t] + bh[t * NBA + blk]) : 0;
    __syncthreads();
    for (int o = 1; o < 256; o <<= 1) {
        int a = (t >= o) ? loff[t - o] : 0;
        __syncthreads();
        loff[t] += a;
        __syncthreads();
    }

    // pass 2: place payload + global position at locally-sorted slot
    #pragma unroll
    for (int e = 0; e < 16; e++) {
        int i = i0 + e * 256 + t;
        if (i < Etot) {
            int s = (i < E) ? ei[i] : (i - E);
            int d = (i < E) ? ei[E + i] : (i - E);
            int b = rb[e] >> 12;
            int r = rb[e] & 0xFFF;
            int slot = loff[b] - h[b] + r;
            su[slot] = s | ((d & 255) << 16);
            sp[slot] = gb[b] + r;
        }
    }
    __syncthreads();

    // pass 3: linear read, mostly-contiguous writes (runs of ~21 per bucket)
    for (int k = t; k < blkcnt; k += 256) {
        srcbuf[sp[k]] = su[k];
    }
}

// ---------- stage 4: per-bucket CSR finalize (LDS-only atomics) ----------
__global__ __launch_bounds__(256) void csr_kernel(const int* __restrict__ bstart,
                                                  int* __restrict__ srcbuf,
                                                  int* __restrict__ rowptr, int N) {
    __shared__ int eb[8192];
    __shared__ unsigned short rr[8192];
    __shared__ int h[256];
    __shared__ int off[256];
    int b = blockIdx.x, t = threadIdx.x;
    int s0 = bstart[b];
    int cnt = bstart[b + 1] - s0;
    if (cnt > 8192) cnt = 8192;            // impossible (mean 4352, sigma 64); safety
    h[t] = 0;
    __syncthreads();
    for (int j = t; j < cnt; j += 256) {
        int u = srcbuf[s0 + j];
        eb[j] = u;
        rr[j] = (unsigned short)atomicAdd(&h[u >> 16], 1);
    }
    __syncthreads();
    off[t] = h[t];
    __syncthreads();
    for (int o = 1; o < 256; o <<= 1) {
        int a = (t >= o) ? off[t - o] : 0;
        __syncthreads();
        off[t] += a;
        __syncthreads();
    }
    int excl = off[t] - h[t];
    int d = b * 256 + t;
    if (d <= N) rowptr[d] = s0 + excl;
    __syncthreads();
    h[t] = excl;                           // reuse h as exclusive bin offsets
    __syncthreads();
    for (int j = t; j < cnt; j += 256) {
        int u = eb[j];
        srcbuf[s0 + h[u >> 16] + rr[j]] = u & 0xFFFF;
    }
}

// ---------- layer-1 aggregation, XCD-SLICED: block (group, slice k) computes a
// 32-channel slice of 4 dsts. slice = bid & 7 -> lands on XCD (bid % 8) so each
// XCD's L2 holds only its 3.2 MB h1b slice (L2-resident gather). Weights for the
// slice's single head are recomputed locally; sa/sb written as per-slice partials.
__global__ __launch_bounds__(256) void aggslice_kernel(const int* __restrict__ rowptr,
                                                       const int* __restrict__ srcbuf,
                                                       const float* __restrict__ ssrc,
                                                       const float* __restrict__ sdst,
                                                       const ushort_t* __restrict__ h1b,
                                                       const float* __restrict__ b1,
                                                       const float* __restrict__ va,
                                                       const float* __restrict__ vb,
                                                       ushort_t* __restrict__ x2b,
                                                       float* __restrict__ sapart,
                                                       float* __restrict__ sbpart, int N) {
    __shared__ int   s_sh[4][64];
    __shared__ float w_sh[4][64];
    int bid = blockIdx.x;
    int k = bid & 7;                       // slice (-> XCD)
    int grp = bid >> 3;
    int lane = threadIdx.x & 63, w = threadIdx.x >> 6;
    int d = grp * 4 + w;
    if (d >= N) return;
    int h = k >> 1;                        // head owning this slice
    int k4 = lane & 3, g = lane >> 2;      // 16 edge-groups x 4 channel-lanes
    int row = rowptr[d], end = rowptr[d + 1];
    float sdv = sdst[d * 4 + h];
    const ushort_t* hsl = h1b + (size_t)k * N * 32;
    float lacc = 0.f;
    float a0 = 0.f, a1 = 0.f, a2 = 0.f, a3 = 0.f;
    float a4 = 0.f, a5 = 0.f, a6 = 0.f, a7 = 0.f;

    for (int base = row; base < end; base += 64) {
        int cnt = min(64, end - base);
        bool valid = lane < cnt;
        int s = valid ? srcbuf[base + lane] : 0;
        float wv = valid ? __expf(lrelu(ssrc[s * 4 + h] + sdv)) : 0.f;
        lacc += wv;
        s_sh[w][lane] = s;
        w_sh[w][lane] = wv;
        // wave-private LDS; lockstep wave, no barrier needed
        int cnt16 = (cnt + 15) & ~15;
        for (int j = 0; j < cnt16; j += 16) {
            int e = j + g;
            int se = s_sh[w][e];
            float we = w_sh[w][e];
            uint4 u = *(const uint4*)(hsl + (size_t)se * 32 + k4 * 8);
            FMAMIX_LO(a0, u.x, we); FMAMIX_HI(a1, u.x, we);
            FMAMIX_LO(a2, u.y, we); FMAMIX_HI(a3, u.y, we);
            FMAMIX_LO(a4, u.z, we); FMAMIX_HI(a5, u.z, we);
            FMAMIX_LO(a6, u.w, we); FMAMIX_HI(a7, u.w, we);
        }
    }
    // reduce over the 16 edge-groups (lane bits 2..5)
    #define GRED(a) { a += __shfl_xor(a, 4, 64); a += __shfl_xor(a, 8, 64); \
                      a += __shfl_xor(a, 16, 64); a += __shfl_xor(a, 32, 64); }
    GRED(a0) GRED(a1) GRED(a2) GRED(a3)
    GRED(a4) GRED(a5) GRED(a6) GRED(a7)
    #undef GRED
    float rl = 1.f / wrsum(lacc);
    int c = k * 32 + k4 * 8;
    float4 b1a = *(const float4*)(b1 + c);
    float4 b1b = *(const float4*)(b1 + c + 4);
    float v0 = a0 * rl + b1a.x, v1 = a1 * rl + b1a.y;
    float v2 = a2 * rl + b1a.z, v3 = a3 * rl + b1a.w;
    float v4 = a4 * rl + b1b.x, v5 = a5 * rl + b1b.y;
    float v6 = a6 * rl + b1b.z, v7 = a7 * rl + b1b.w;
    v0 = v0 > 0.f ? v0 : __expf(v0) - 1.f;
    v1 = v1 > 0.f ? v1 : __expf(v1) - 1.f;
    v2 = v2 > 0.f ? v2 : __expf(v2) - 1.f;
    v3 = v3 > 0.f ? v3 : __expf(v3) - 1.f;
    v4 = v4 > 0.f ? v4 : __expf(v4) - 1.f;
    v5 = v5 > 0.f ? v5 : __expf(v5) - 1.f;
    v6 = v6 > 0.f ? v6 : __expf(v6) - 1.f;
    v7 = v7 > 0.f ? v7 : __expf(v7) - 1.f;
    if (g == 0) {                          // lanes 0..3 write the 64B x2b slice
        unsigned p0 = (unsigned)f2h(v0) | ((unsigned)f2h(v1) << 16);
        unsigned p1 = (unsigned)f2h(v2) | ((unsigned)f2h(v3) << 16);
        unsigned p2 = (unsigned)f2h(v4) | ((unsigned)f2h(v5) << 16);
        unsigned p3 = (unsigned)f2h(v6) | ((unsigned)f2h(v7) << 16);
        *(uint4*)(x2b + (size_t)k * N * 32 + (size_t)d * 32 + k4 * 8)
            = make_uint4(p0, p1, p2, p3);
    }
    float4 vaa = *(const float4*)(va + c), vab = *(const float4*)(va + c + 4);
    float4 vba = *(const float4*)(vb + c), vbb = *(const float4*)(vb + c + 4);
    float sa = v0 * vaa.x + v1 * vaa.y + v2 * vaa.z + v3 * vaa.w
             + v4 * vab.x + v5 * vab.y + v6 * vab.z + v7 * vab.w;
    float sb = v0 * vba.x + v1 * vba.y + v2 * vba.z + v3 * vba.w
             + v4 * vbb.x + v5 * vbb.y + v6 * vbb.z + v7 * vbb.w;
    sa += __shfl_xor(sa, 1, 64); sa += __shfl_xor(sa, 2, 64);  // combine 4 k4 lanes
    sb += __shfl_xor(sb, 1, 64); sb += __shfl_xor(sb, 2, 64);
    if (lane == 0) { sapart[d * 8 + k] = sa; sbpart[d * 8 + k] = sb; }
}

// ---------- gemmz via MFMA (f16): z = x2b @ W2 + b2 (sliced x2b), + partial-sum fold ----------
__global__ __launch_bounds__(256) void gemmz_kernel(const ushort_t* __restrict__ x2b,
                                                    const ushort_t* __restrict__ W2s,
                                                    const float* __restrict__ b2,
                                                    const float* __restrict__ sapart,
                                                    const float* __restrict__ sbpart,
                                                    float* __restrict__ ssrc2,
                                                    float* __restrict__ sdst2,
                                                    ushort_t* __restrict__ zh, int N) {
    int base = blockIdx.x * 32;
    int tid = threadIdx.x;
    if (tid < 32) {                        // fold per-slice sa/sb partials
        int r = base + tid;
        if (r < N) {
            float sa = 0.f, sb = 0.f;
            #pragma unroll
            for (int k = 0; k < 8; k++) {
                sa += sapart[r * 8 + k];
                sb += sbpart[r * 8 + k];
            }
            ssrc2[r] = sa;
            sdst2[r] = sb;
        }
    }
    int lane = tid & 63, wv = tid >> 6;
    int m = lane & 15, q = lane >> 4;
    int c = wv * 16 + m;
    float bc = b2[c];

    #pragma unroll
    for (int h = 0; h < 2; h++) {
        int rbase = base + h * 16;
        bool rowok = (rbase + m) < N;
        f32x4 acc = {0.f, 0.f, 0.f, 0.f};
        #pragma unroll
        for (int kc = 0; kc < 8; kc++) {   // kc = channel slice
            f16x8 af = {0, 0, 0, 0, 0, 0, 0, 0};
            if (rowok) af = *(const f16x8*)(x2b + (size_t)kc * N * 32
                                            + (size_t)(rbase + m) * 32 + q * 8);
            f16x8 bf = *(const f16x8*)(W2s + (((size_t)(kc * 4 + wv) * 64 + lane) << 3));
            acc = __builtin_amdgcn_mfma_f32_16x16x32_f16(af, bf, acc, 0, 0, 0);
        }
        #pragma unroll
        for (int reg = 0; reg < 4; reg++) {
            int n = rbase + q * 4 + reg;
            if (n < N) zh[(size_t)n * 64 + c] = f2h(acc[reg] + bc);
        }
    }
}

// ---------- layer-2 aggregation: 8-lane-group uint4 gathers (one full 128B row per group) ----------
__global__ __launch_bounds__(256) void aggz_kernel(const int* __restrict__ rowptr,
                                                   const int* __restrict__ srcbuf,
                                                   const float* __restrict__ ssrc,
                                                   const float* __restrict__ sdst,
                                                   const ushort_t* __restrict__ zh,
                                                   unsigned* __restrict__ minenc, int N) {
    __shared__ int   s_sh[4][64];
    __shared__ float w_sh[4][64];
    __shared__ float smc[4][64];
    int lane = threadIdx.x & 63, w = threadIdx.x >> 6;
    int k = lane & 7, g = lane >> 3;
    float m0 = INFINITY, m1 = INFINITY, m2 = INFINITY, m3 = INFINITY;
    float m4 = INFINITY, m5 = INFINITY, m6 = INFINITY, m7 = INFINITY;

    for (int d0 = blockIdx.x * 4; d0 < N; d0 += gridDim.x * 4) {
        int d = d0 + w;
        if (d < N) {
            int row = rowptr[d], end = rowptr[d + 1];
            float sdv = sdst[d];
            float lacc = 0.f;
            float a0 = 0.f, a1 = 0.f, a2 = 0.f, a3 = 0.f;
            float a4 = 0.f, a5 = 0.f, a6 = 0.f, a7 = 0.f;
            for (int base = row; base < end; base += 64) {
                int cnt = min(64, end - base);
                bool valid = lane < cnt;
                int s = valid ? srcbuf[base + lane] : 0;
                float wt = valid ? __expf(lrelu(ssrc[s] + sdv)) : 0.f;
                lacc += wt;
                s_sh[w][lane] = s;
                w_sh[w][lane] = wt;
                // wave-private LDS; lockstep wave
                int cnt8 = (cnt + 7) & ~7;
                for (int j = 0; j < cnt8; j += 8) {
                    int e = j + g;
                    int sj = s_sh[w][e];
                    float wj = w_sh[w][e];
                    uint4 u = *(const uint4*)(zh + (size_t)sj * 64 + k * 8);
                    FMAMIX_LO(a0, u.x, wj); FMAMIX_HI(a1, u.x, wj);
                    FMAMIX_LO(a2, u.y, wj); FMAMIX_HI(a3, u.y, wj);
                    FMAMIX_LO(a4, u.z, wj); FMAMIX_HI(a5, u.z, wj);
                    FMAMIX_LO(a6, u.w, wj); FMAMIX_HI(a7, u.w, wj);
                }
            }
            // reduce over the 8 edge-groups (lane bits 3..5)
            #define GRED(a) { a += __shfl_xor(a, 8, 64); a += __shfl_xor(a, 16, 64); a += __shfl_xor(a, 32, 64); }
            GRED(a0) GRED(a1) GRED(a2) GRED(a3)
            GRED(a4) GRED(a5) GRED(a6) GRED(a7)
            #undef GRED
            float rl = 1.f / wrsum(lacc);
            m0 = fminf(m0, a0 * rl); m1 = fminf(m1, a1 * rl);
            m2 = fminf(m2, a2 * rl); m3 = fminf(m3, a3 * rl);
            m4 = fminf(m4, a4 * rl); m5 = fminf(m5, a5 * rl);
            m6 = fminf(m6, a6 * rl); m7 = fminf(m7, a7 * rl);
        }
    }
    if (g == 0) {                          // lanes 0..7: channels 8k..8k+7
        float* sp = &smc[w][k * 8];
        sp[0] = m0; sp[1] = m1; sp[2] = m2; sp[3] = m3;
        sp[4] = m4; sp[5] = m5; sp[6] = m6; sp[7] = m7;
    }
    __syncthreads();
    if (w == 0) {
        float v = fminf(fminf(smc[0][lane], smc[1][lane]),
                        fminf(smc[2][lane], smc[3][lane]));
        atomicMin(&minenc[lane], fenc(v));
    }
}

__global__ void decode_kernel(const unsigned* __restrict__ minenc, float* __restrict__ out) {
    int d = threadIdx.x;
    if (d < 64) out[d] = fdec(minenc[d]);
}

// ---------- launch ----------
extern "C" void kernel_launch(void* const* d_in, const int* in_sizes, int n_in,
                              void* d_out, int out_size, void* d_ws, size_t ws_size,
                              hipStream_t stream) {
    const float* x      = (const float*)d_in[0];
    const int*   ei     = (const int*)d_in[1];
    const float* W1     = (const float*)d_in[2];
    const float* a_src1 = (const float*)d_in[3];
    const float* a_dst1 = (const float*)d_in[4];
    const float* b1     = (const float*)d_in[5];
    const float* W2     = (const float*)d_in[6];
    const float* a_src2 = (const float*)d_in[7];
    const float* a_dst2 = (const float*)d_in[8];
    const float* b2     = (const float*)d_in[9];
    float* out = (float*)d_out;

    const int N = in_sizes[0] / 128;
    const int E = in_sizes[1] / 2;
    const int Etot = E + N;
    const int Epad = Etot + 64;
    const int M = N + 1;

    const int BB  = ((N - 1) >> 8) + 1;    // dst buckets (dst>>8), 196 for N=50000
    const int NBA = (Etot + 4095) / 4096;  // hist chunks, 208 for Etot=850000 (<=256)

    // workspace layout (4-byte words; N divisible by 4 keeps 16B alignment)
    float* ws = (float*)d_ws;
    ushort_t* h1b = (ushort_t*)ws;                     // N*256 f16 (sliced) = N*128 words
    ushort_t* x2b = (ushort_t*)(ws + (size_t)N * 128); // N*256 f16 (sliced)
    ushort_t* zh  = (ushort_t*)(ws + (size_t)N * 256); // N*64 f16 (region N*64 words)
    ushort_t* W1s = (ushort_t*)(ws + (size_t)N * 320); // 32768 f16 = 16384 words
    ushort_t* W2s = (ushort_t*)(ws + (size_t)N * 320 + 16384); // 16384 f16 = 8192 words
    float* ssrc1  = ws + (size_t)N * 320 + 24576;      // 4N (16B aligned)
    float* sdst1  = ssrc1 + (size_t)N * 4;             // 4N
    float* ssrc2  = sdst1 + (size_t)N * 4;             // N
    float* sdst2  = ssrc2 + N;                         // N
    float* va     = sdst2 + N;                         // 256
    float* vb     = va + 256;                          // 256
    int*   bh     = (int*)(vb + 256);                  // BB*NBA (<= M = N+1 words)
    int*   rowptr = bh + M;                            // N+1
    int*   gtot   = rowptr + M;                        // 256
    int*   bstart = gtot + 256;                        // 256 (BB+1 used)
    int*   srcbuf = bstart + 256;                      // Epad
    unsigned* minenc = (unsigned*)(srcbuf + Epad);     // 64
    float* sapart = (float*)(minenc + 64);             // 8N
    float* sbpart = sapart + (size_t)N * 8;            // 8N

    int nb16 = (N + 15) / 16;
    int nb32 = (N + 31) / 32;
    int nbs = ((N + 3) / 4) * 8;           // aggslice: 8 slices per dst-group
    int nbz = 2048;                        // grid-stride; 8 blocks/CU

    pre_kernel<<<193, 256, 0, stream>>>(W1, W2, a_src2, a_dst2, W1s, W2s, va, vb,
                                        minenc, gtot);
    front_kernel<<<nb16 + NBA, 256, 0, stream>>>(x, W1s, a_src1, a_dst1, h1b, ssrc1, sdst1,
                                                 ei, bh, gtot, N, E, Etot, nb16, NBA, BB);
    scan2_kernel<<<BB + 1, 256, 0, stream>>>(bh, gtot, bstart, NBA, BB);
    scat_kernel<<<NBA, 256, 0, stream>>>(ei, bh, bstart, srcbuf, E, Etot, NBA, BB);
    csr_kernel<<<BB, 256, 0, stream>>>(bstart, srcbuf, rowptr, N);

    aggslice_kernel<<<nbs, 256, 0, stream>>>(rowptr, srcbuf, ssrc1, sdst1, h1b, b1,
                                             va, vb, x2b, sapart, sbpart, N);
    gemmz_kernel<<<nb32, 256, 0, stream>>>(x2b, W2s, b2, sapart, sbpart,
                                           ssrc2, sdst2, zh, N);
    aggz_kernel<<<nbz, 256, 0, stream>>>(rowptr, srcbuf, ssrc2, sdst2, zh, minenc, N);
    decode_kernel<<<1, 64, 0, stream>>>(minenc, out);
}

// Round 10
// 267.873 us; speedup vs baseline: 1.4646x; 1.4646x over previous
//
#include <hip/hip_runtime.h>
#include <math.h>

typedef unsigned short ushort_t;
typedef __attribute__((ext_vector_type(8))) _Float16 f16x8;
typedef __attribute__((ext_vector_type(4))) float f32x4;

// ---------- helpers ----------

__device__ inline unsigned fenc(float f) {
    unsigned u = __float_as_uint(f);
    return (u & 0x80000000u) ? ~u : (u | 0x80000000u);
}
__device__ inline float fdec(unsigned u) {
    return __uint_as_float((u & 0x80000000u) ? (u ^ 0x80000000u) : ~u);
}

__device__ inline float wrsum(float v) {
    #pragma unroll
    for (int m = 32; m; m >>= 1) v += __shfl_xor(v, m, 64);
    return v;
}
__device__ inline float lrelu(float x) { return x > 0.f ? x : 0.2f * x; }

__device__ inline ushort_t f2h(float f) {
    _Float16 h = (_Float16)f;              // RNE
    union { _Float16 h; ushort_t u; } cv;
    cv.h = h;
    return cv.u;
}

// acc += f16(lo half of pk) * w   /   acc += f16(hi half of pk) * w
#define FMAMIX_LO(acc, pk, w) \
    asm("v_fma_mix_f32 %0, %1, %2, %0 op_sel:[0,0,0] op_sel_hi:[1,0,0]" \
        : "+v"(acc) : "v"(pk), "v"(w))
#define FMAMIX_HI(acc, pk, w) \
    asm("v_fma_mix_f32 %0, %1, %2, %0 op_sel:[1,0,0] op_sel_hi:[1,0,0]" \
        : "+v"(acc) : "v"(pk), "v"(w))

// ---------- pre kernel: W swizzles + vab + inits ----------
__global__ __launch_bounds__(256) void pre_kernel(const float* __restrict__ W1,
                                                  const float* __restrict__ W2,
                                                  const float* __restrict__ a_src2,
                                                  const float* __restrict__ a_dst2,
                                                  ushort_t* __restrict__ W1s,
                                                  ushort_t* __restrict__ W2s,
                                                  float* __restrict__ va,
                                                  float* __restrict__ vb,
                                                  unsigned* __restrict__ minenc,
                                                  int* __restrict__ gtot) {
    int bid = blockIdx.x;
    int tid = threadIdx.x;
    if (bid < 128) {                       // W1 swizzle: 32768 elems
        int idx = bid * 256 + tid;
        int j = idx & 7;
        int lane = (idx >> 3) & 63;
        int ct = (idx >> 9) & 15;
        int kc = (idx >> 13) & 3;
        int k = kc * 32 + (lane >> 4) * 8 + j;
        int c = ct * 16 + (lane & 15);
        W1s[idx] = f2h(W1[k * 256 + c]);
    } else if (bid < 192) {                // W2 swizzle: 16384 elems
        int idx = (bid - 128) * 256 + tid;
        int j = idx & 7;
        int lane = (idx >> 3) & 63;
        int ct = (idx >> 9) & 3;
        int kc = idx >> 11;
        int k = kc * 32 + (lane >> 4) * 8 + j;
        int c = ct * 16 + (lane & 15);
        W2s[idx] = f2h(W2[k * 64 + c]);
    } else {                               // vab + minenc/gtot init
        int k = tid;
        float sa = 0.f, sb = 0.f;
        #pragma unroll 8
        for (int c = 0; c < 64; c++) {
            float w = W2[k * 64 + c];
            sa += w * a_src2[c];
            sb += w * a_dst2[c];
        }
        va[k] = sa;
        vb[k] = sb;
        if (tid < 64) minenc[tid] = 0xFFFFFFFFu;
        gtot[tid] = 0;
    }
}

// ---------- front kernel: MFMA gemm1 (f16) + scores1, with hist blocks appended ----------
__global__ __launch_bounds__(256) void front_kernel(const float* __restrict__ x,
                                                    const ushort_t* __restrict__ W1s,
                                                    const float* __restrict__ a_src,
                                                    const float* __restrict__ a_dst,
                                                    ushort_t* __restrict__ h1b,
                                                    float* __restrict__ ssrc,
                                                    float* __restrict__ sdst,
                                                    const int* __restrict__ ei,
                                                    int* __restrict__ bh,
                                                    int* __restrict__ gtot,
                                                    int N, int E, int Etot,
                                                    int nb16, int NBA, int BB) {
    __shared__ float ss[16 * 257];         // aliased: x staging first, D-tile after
    __shared__ float ps[256];
    int bid = blockIdx.x;
    int tid = threadIdx.x;

    if (bid >= nb16) {                     // ---- hist ----
        int* h = (int*)ps;
        int blk = bid - nb16;
        h[tid] = 0;
        __syncthreads();
        int i0 = blk * 4096 + tid;
        #pragma unroll
        for (int e = 0; e < 16; e++) {
            int i = i0 + e * 256;
            if (i < Etot) {
                int d = (i < E) ? ei[E + i] : (i - E);
                atomicAdd(&h[d >> 8], 1);
            }
        }
        __syncthreads();
        if (tid < BB) {
            bh[tid * NBA + blk] = h[tid];
            atomicAdd(&gtot[tid], h[tid]);
        }
        return;
    }

    // ---- stage x tile into LDS (coalesced; rows padded to 33 float4 = 132 floats) ----
    int base = bid * 16;
    {
        const float4* xv = (const float4*)(x + (size_t)base * 128);
        float4* xs4 = (float4*)ss;
        #pragma unroll
        for (int i = tid; i < 512; i += 256) {
            int row = i >> 5;              // 32 float4 per row
            float4 v = (base + row < N) ? xv[i] : make_float4(0.f, 0.f, 0.f, 0.f);
            xs4[row * 33 + (i & 31)] = v;
        }
    }
    __syncthreads();

    // ---- build A-fragments from LDS ----
    int lane = tid & 63, wv = tid >> 6;
    int m = lane & 15, q = lane >> 4;
    f16x8 afrag[4];
    #pragma unroll
    for (int kc = 0; kc < 4; kc++) {
        const float* xp = ss + m * 132 + kc * 32 + q * 8;
        float4 xa = *(const float4*)xp;
        float4 xb = *(const float4*)(xp + 4);
        f16x8 af;
        af[0] = (_Float16)xa.x; af[1] = (_Float16)xa.y;
        af[2] = (_Float16)xa.z; af[3] = (_Float16)xa.w;
        af[4] = (_Float16)xb.x; af[5] = (_Float16)xb.y;
        af[6] = (_Float16)xb.z; af[7] = (_Float16)xb.w;
        afrag[kc] = af;
    }
    __syncthreads();                       // xs dead; ss reused for D-tiles

    #pragma unroll
    for (int t = 0; t < 4; t++) {
        int ct = wv * 4 + t;
        f32x4 acc = {0.f, 0.f, 0.f, 0.f};
        #pragma unroll
        for (int kc = 0; kc < 4; kc++) {
            f16x8 bfrag = *(const f16x8*)(W1s + (((size_t)(kc * 16 + ct) * 64 + lane) << 3));
            acc = __builtin_amdgcn_mfma_f32_16x16x32_f16(afrag[kc], bfrag, acc, 0, 0, 0);
        }
        #pragma unroll
        for (int reg = 0; reg < 4; reg++) {
            ss[(q * 4 + reg) * 257 + ct * 16 + m] = acc[reg];
        }
    }
    __syncthreads();

    // ---- dense h1b writes: CHANNEL-CONTIGUOUS rows (h1b[n][c], c=0..255) ----
    // thread (j, dd) packs channels dd*4 .. dd*4+3 into one uint2.
    int dd = tid & 63, jj = tid >> 6;
    #pragma unroll
    for (int t2 = 0; t2 < 4; t2++) {
        int j = jj + t2 * 4;
        int n = base + j;
        if (n < N) {
            const float* row = ss + j * 257 + dd * 4;
            unsigned p0 = (unsigned)f2h(row[0]) | ((unsigned)f2h(row[1]) << 16);
            unsigned p1 = (unsigned)f2h(row[2]) | ((unsigned)f2h(row[3]) << 16);
            *(uint2*)(h1b + (size_t)n * 256 + dd * 4) = make_uint2(p0, p1);
        }
    }
    // ---- scores via partial sums (hh2-rotated) ----
    int j = tid & 15, hh2 = (tid >> 4) & 3, which = (tid >> 6) & 1, half = tid >> 7;
    const float* av = which ? a_dst : a_src;
    int cbase = hh2 * 64 + half * 32;
    float sum = 0.f;
    #pragma unroll
    for (int i = 0; i < 32; i++) {
        int ii = (i + 8 * hh2) & 31;
        sum += ss[j * 257 + cbase + ii] * av[cbase + ii];
    }
    ps[tid] = sum;
    __syncthreads();
    if (half == 0) {
        float tot = sum + ps[tid + 128];
        int n = base + j;
        if (n < N) (which ? sdst : ssrc)[n * 4 + hh2] = tot;
    }
}

// ---------- scan2: blocks 0..BB-1 scan bh rows over chunks; block BB scans gtot ----------
__global__ __launch_bounds__(256) void scan2_kernel(int* __restrict__ bh,
                                                    const int* __restrict__ gtot,
                                                    int* __restrict__ bstart,
                                                    int NBA, int BB) {
    __shared__ int sm[256];
    int b = blockIdx.x, t = threadIdx.x;
    if (b < BB) {                          // per-bucket exclusive scan over blocks
        int v = (t < NBA) ? bh[b * NBA + t] : 0;
        sm[t] = v;
        __syncthreads();
        for (int o = 1; o < 256; o <<= 1) {
            int a = (t >= o) ? sm[t - o] : 0;
            __syncthreads();
            sm[t] += a;
            __syncthreads();
        }
        if (t < NBA) bh[b * NBA + t] = sm[t] - v;
    } else {                               // bucket-level exclusive scan
        int v = (t < BB) ? gtot[t] : 0;
        sm[t] = v;
        __syncthreads();
        for (int o = 1; o < 256; o <<= 1) {
            int a = (t >= o) ? sm[t - o] : 0;
            __syncthreads();
            sm[t] += a;
            __syncthreads();
        }
        if (t < BB) bstart[t] = sm[t] - v;
        if (t == BB - 1) bstart[BB] = sm[t];
    }
}

// ---------- scat: recompute local ranks, block-local counting sort, run-coalesced writes ----------
__global__ __launch_bounds__(256) void scat_kernel(const int* __restrict__ ei,
                                                   const int* __restrict__ bh,
                                                   const int* __restrict__ bstart,
                                                   int* __restrict__ srcbuf,
                                                   int E, int Etot, int NBA, int BB) {
    __shared__ int h[256];
    __shared__ int loff[256];
    __shared__ int gb[256];
    __shared__ int su[4096];
    __shared__ int sp[4096];
    int t = threadIdx.x, blk = blockIdx.x;
    h[t] = 0;
    __syncthreads();
    int i0 = blk * 4096;
    int blkcnt = min(4096, Etot - i0);

    // pass 1: (bucket, rank) per edge via LDS atomics (counts match hist deterministically)
    int rb[16];
    #pragma unroll
    for (int e = 0; e < 16; e++) {
        int i = i0 + e * 256 + t;
        rb[e] = -1;
        if (i < Etot) {
            int d = (i < E) ? ei[E + i] : (i - E);
            int b = d >> 8;
            int r = atomicAdd(&h[b], 1);
            rb[e] = (b << 12) | r;         // r < 4096
        }
    }
    __syncthreads();

    // local exclusive offsets + global bases
    loff[t] = h[t];
    gb[t] = (t < BB) ? (bstart[t] + bh[t * NBA + blk]) : 0;
    __syncthreads();
    for (int o = 1; o < 256; o <<= 1) {
        int a = (t >= o) ? loff[t - o] : 0;
        __syncthreads();
        loff[t] += a;
        __syncthreads();
    }

    // pass 2: place payload + global position at locally-sorted slot
    #pragma unroll
    for (int e = 0; e < 16; e++) {
        int i = i0 + e * 256 + t;
        if (i < Etot) {
            int s = (i < E) ? ei[i] : (i - E);
            int d = (i < E) ? ei[E + i] : (i - E);
            int b = rb[e] >> 12;
            int r = rb[e] & 0xFFF;
            int slot = loff[b] - h[b] + r;
            su[slot] = s | ((d & 255) << 16);
            sp[slot] = gb[b] + r;
        }
    }
    __syncthreads();

    // pass 3: linear read, mostly-contiguous writes (runs of ~21 per bucket)
    for (int k = t; k < blkcnt; k += 256) {
        srcbuf[sp[k]] = su[k];
    }
}

// ---------- stage 4: per-bucket CSR finalize (LDS-only atomics) ----------
__global__ __launch_bounds__(256) void csr_kernel(const int* __restrict__ bstart,
                                                  int* __restrict__ srcbuf,
                                                  int* __restrict__ rowptr, int N) {
    __shared__ int eb[8192];
    __shared__ unsigned short rr[8192];
    __shared__ int h[256];
    __shared__ int off[256];
    int b = blockIdx.x, t = threadIdx.x;
    int s0 = bstart[b];
    int cnt = bstart[b + 1] - s0;
    if (cnt > 8192) cnt = 8192;            // impossible (mean 4352, sigma 64); safety
    h[t] = 0;
    __syncthreads();
    for (int j = t; j < cnt; j += 256) {
        int u = srcbuf[s0 + j];
        eb[j] = u;
        rr[j] = (unsigned short)atomicAdd(&h[u >> 16], 1);
    }
    __syncthreads();
    off[t] = h[t];
    __syncthreads();
    for (int o = 1; o < 256; o <<= 1) {
        int a = (t >= o) ? off[t - o] : 0;
        __syncthreads();
        off[t] += a;
        __syncthreads();
    }
    int excl = off[t] - h[t];
    int d = b * 256 + t;
    if (d <= N) rowptr[d] = s0 + excl;
    __syncthreads();
    h[t] = excl;                           // reuse h as exclusive bin offsets
    __syncthreads();
    for (int j = t; j < cnt; j += 256) {
        int u = eb[j];
        srcbuf[s0 + h[u >> 16] + rr[j]] = u & 0xFFFF;
    }
}

// ---------- layer-1 aggregation: half-wave uint4 gathers, 4-deep MLP, end reductions ----------
__global__ __launch_bounds__(256) void agg1_kernel(const int* __restrict__ rowptr,
                                                   const int* __restrict__ srcbuf,
                                                   const float* __restrict__ ssrc,
                                                   const float* __restrict__ sdst,
                                                   const ushort_t* __restrict__ h1b,
                                                   const float* __restrict__ b1,
                                                   const float* __restrict__ va,
                                                   const float* __restrict__ vb,
                                                   ushort_t* __restrict__ x2b,
                                                   float* __restrict__ ssrc2,
                                                   float* __restrict__ sdst2, int N) {
    __shared__ int    s_sh[4][64];
    __shared__ float4 w_sh[4][64];
    int lane = threadIdx.x & 63, w = threadIdx.x >> 6;
    int li = lane & 31, half = lane >> 5;
    int hh = li >> 3;                      // head owning channels [8*li, 8*li+8)
    int d = blockIdx.x * 4 + w;
    if (d >= N) return;
    int row = rowptr[d], end = rowptr[d + 1];
    float4 sd = *(const float4*)(sdst + d * 4);
    float lx = 0.f, ly = 0.f, lz = 0.f, lw = 0.f;
    float a0 = 0.f, a1 = 0.f, a2 = 0.f, a3 = 0.f;
    float a4 = 0.f, a5 = 0.f, a6 = 0.f, a7 = 0.f;

    for (int base = row; base < end; base += 64) {
        int cnt = min(64, end - base);
        bool valid = lane < cnt;
        int s = valid ? srcbuf[base + lane] : 0;
        float4 ssv = *(const float4*)(ssrc + s * 4);
        float w0 = valid ? __expf(lrelu(ssv.x + sd.x)) : 0.f;
        float w1 = valid ? __expf(lrelu(ssv.y + sd.y)) : 0.f;
        float w2 = valid ? __expf(lrelu(ssv.z + sd.z)) : 0.f;
        float w3 = valid ? __expf(lrelu(ssv.w + sd.w)) : 0.f;
        lx += w0; ly += w1; lz += w2; lw += w3;
        s_sh[w][lane] = s;
        w_sh[w][lane] = make_float4(w0, w1, w2, w3);
        // wave-private LDS; lockstep wave, no barrier needed
        // 4 gathers in flight per half-wave (8 edges per iteration)
        int cnt8 = (cnt + 7) & ~7;
        for (int j = 0; j < cnt8; j += 8) {
            int ea = j + half, eb = j + 2 + half, ec = j + 4 + half, ed = j + 6 + half;
            int sa_ = s_sh[w][ea], sb_ = s_sh[w][eb], sc_ = s_sh[w][ec], sd_ = s_sh[w][ed];
            float wa = ((const float*)(w_sh[w] + ea))[hh];
            float wb = ((const float*)(w_sh[w] + eb))[hh];
            float wc = ((const float*)(w_sh[w] + ec))[hh];
            float wd = ((const float*)(w_sh[w] + ed))[hh];
            uint4 ua = *(const uint4*)(h1b + (size_t)sa_ * 256 + li * 8);
            uint4 ub = *(const uint4*)(h1b + (size_t)sb_ * 256 + li * 8);
            uint4 uc = *(const uint4*)(h1b + (size_t)sc_ * 256 + li * 8);
            uint4 ud = *(const uint4*)(h1b + (size_t)sd_ * 256 + li * 8);
            FMAMIX_LO(a0, ua.x, wa); FMAMIX_HI(a1, ua.x, wa);
            FMAMIX_LO(a2, ua.y, wa); FMAMIX_HI(a3, ua.y, wa);
            FMAMIX_LO(a4, ua.z, wa); FMAMIX_HI(a5, ua.z, wa);
            FMAMIX_LO(a6, ua.w, wa); FMAMIX_HI(a7, ua.w, wa);
            FMAMIX_LO(a0, ub.x, wb); FMAMIX_HI(a1, ub.x, wb);
            FMAMIX_LO(a2, ub.y, wb); FMAMIX_HI(a3, ub.y, wb);
            FMAMIX_LO(a4, ub.z, wb); FMAMIX_HI(a5, ub.z, wb);
            FMAMIX_LO(a6, ub.w, wb); FMAMIX_HI(a7, ub.w, wb);
            FMAMIX_LO(a0, uc.x, wc); FMAMIX_HI(a1, uc.x, wc);
            FMAMIX_LO(a2, uc.y, wc); FMAMIX_HI(a3, uc.y, wc);
            FMAMIX_LO(a4, uc.z, wc); FMAMIX_HI(a5, uc.z, wc);
            FMAMIX_LO(a6, uc.w, wc); FMAMIX_HI(a7, uc.w, wc);
            FMAMIX_LO(a0, ud.x, wd); FMAMIX_HI(a1, ud.x, wd);
            FMAMIX_LO(a2, ud.y, wd); FMAMIX_HI(a3, ud.y, wd);
            FMAMIX_LO(a4, ud.z, wd); FMAMIX_HI(a5, ud.z, wd);
            FMAMIX_LO(a6, ud.w, wd); FMAMIX_HI(a7, ud.w, wd);
        }
    }
    // combine halves (lanes li and li+32 hold the two edge-subsets of same channels)
    a0 += __shfl_xor(a0, 32, 64); a1 += __shfl_xor(a1, 32, 64);
    a2 += __shfl_xor(a2, 32, 64); a3 += __shfl_xor(a3, 32, 64);
    a4 += __shfl_xor(a4, 32, 64); a5 += __shfl_xor(a5, 32, 64);
    a6 += __shfl_xor(a6, 32, 64); a7 += __shfl_xor(a7, 32, 64);
    // denominators: one reduction per head at the end
    float l0 = wrsum(lx), l1 = wrsum(ly), l2 = wrsum(lz), l3 = wrsum(lw);
    float lh = hh == 0 ? l0 : hh == 1 ? l1 : hh == 2 ? l2 : l3;
    float rl = 1.f / lh;
    int c8 = li * 8;
    float4 b1a = *(const float4*)(b1 + c8);
    float4 b1b = *(const float4*)(b1 + c8 + 4);
    float v0 = a0 * rl + b1a.x, v1 = a1 * rl + b1a.y;
    float v2 = a2 * rl + b1a.z, v3 = a3 * rl + b1a.w;
    float v4 = a4 * rl + b1b.x, v5 = a5 * rl + b1b.y;
    float v6 = a6 * rl + b1b.z, v7 = a7 * rl + b1b.w;
    v0 = v0 > 0.f ? v0 : __expf(v0) - 1.f;
    v1 = v1 > 0.f ? v1 : __expf(v1) - 1.f;
    v2 = v2 > 0.f ? v2 : __expf(v2) - 1.f;
    v3 = v3 > 0.f ? v3 : __expf(v3) - 1.f;
    v4 = v4 > 0.f ? v4 : __expf(v4) - 1.f;
    v5 = v5 > 0.f ? v5 : __expf(v5) - 1.f;
    v6 = v6 > 0.f ? v6 : __expf(v6) - 1.f;
    v7 = v7 > 0.f ? v7 : __expf(v7) - 1.f;
    if (half == 0) {
        unsigned p0 = (unsigned)f2h(v0) | ((unsigned)f2h(v1) << 16);
        unsigned p1 = (unsigned)f2h(v2) | ((unsigned)f2h(v3) << 16);
        unsigned p2 = (unsigned)f2h(v4) | ((unsigned)f2h(v5) << 16);
        unsigned p3 = (unsigned)f2h(v6) | ((unsigned)f2h(v7) << 16);
        *(uint4*)(x2b + (size_t)d * 256 + c8) = make_uint4(p0, p1, p2, p3);
    }
    float4 vaa = *(const float4*)(va + c8), vab = *(const float4*)(va + c8 + 4);
    float4 vba = *(const float4*)(vb + c8), vbb = *(const float4*)(vb + c8 + 4);
    float sa = v0 * vaa.x + v1 * vaa.y + v2 * vaa.z + v3 * vaa.w
             + v4 * vab.x + v5 * vab.y + v6 * vab.z + v7 * vab.w;
    float sb = v0 * vba.x + v1 * vba.y + v2 * vba.z + v3 * vba.w
             + v4 * vbb.x + v5 * vbb.y + v6 * vbb.z + v7 * vbb.w;
    sa = wrsum(sa) * 0.5f;                 // values duplicated across halves
    sb = wrsum(sb) * 0.5f;
    if (lane == 0) { ssrc2[d] = sa; sdst2[d] = sb; }
}

// ---------- gemmz via MFMA (f16): z = x2b @ W2 + b2, stored f16 (N x 64) ----------
__global__ __launch_bounds__(256) void gemmz_kernel(const ushort_t* __restrict__ x2b,
                                                    const ushort_t* __restrict__ W2s,
                                                    const float* __restrict__ b2,
                                                    ushort_t* __restrict__ zh, int N) {
    int base = blockIdx.x * 32;
    int tid = threadIdx.x;
    int lane = tid & 63, wv = tid >> 6;
    int m = lane & 15, q = lane >> 4;
    int c = wv * 16 + m;
    float bc = b2[c];

    #pragma unroll
    for (int h = 0; h < 2; h++) {
        int rbase = base + h * 16;
        bool rowok = (rbase + m) < N;
        const ushort_t* xrow = x2b + (size_t)(rbase + m) * 256;
        f32x4 acc = {0.f, 0.f, 0.f, 0.f};
        #pragma unroll
        for (int kc = 0; kc < 8; kc++) {
            f16x8 af = {0, 0, 0, 0, 0, 0, 0, 0};
            if (rowok) af = *(const f16x8*)(xrow + kc * 32 + q * 8);
            f16x8 bf = *(const f16x8*)(W2s + (((size_t)(kc * 4 + wv) * 64 + lane) << 3));
            acc = __builtin_amdgcn_mfma_f32_16x16x32_f16(af, bf, acc, 0, 0, 0);
        }
        #pragma unroll
        for (int reg = 0; reg < 4; reg++) {
            int n = rbase + q * 4 + reg;
            if (n < N) zh[(size_t)n * 64 + c] = f2h(acc[reg] + bc);
        }
    }
}

// ---------- layer-2 aggregation: 8-lane-group uint4 gathers, 2-deep MLP ----------
// group g = lane>>3 processes edges j+g and j+8+g; lane k = lane&7 covers
// channels [8k, 8k+8). Two uint4 gathers in flight per lane per iteration.
__global__ __launch_bounds__(256) void aggz_kernel(const int* __restrict__ rowptr,
                                                   const int* __restrict__ srcbuf,
                                                   const float* __restrict__ ssrc,
                                                   const float* __restrict__ sdst,
                                                   const ushort_t* __restrict__ zh,
                                                   unsigned* __restrict__ minenc, int N) {
    __shared__ int   s_sh[4][64];
    __shared__ float w_sh[4][64];
    __shared__ float smc[4][64];
    int lane = threadIdx.x & 63, w = threadIdx.x >> 6;
    int k = lane & 7, g = lane >> 3;
    float m0 = INFINITY, m1 = INFINITY, m2 = INFINITY, m3 = INFINITY;
    float m4 = INFINITY, m5 = INFINITY, m6 = INFINITY, m7 = INFINITY;

    for (int d0 = blockIdx.x * 4; d0 < N; d0 += gridDim.x * 4) {
        int d = d0 + w;
        if (d < N) {
            int row = rowptr[d], end = rowptr[d + 1];
            float sdv = sdst[d];
            float lacc = 0.f;
            float a0 = 0.f, a1 = 0.f, a2 = 0.f, a3 = 0.f;
            float a4 = 0.f, a5 = 0.f, a6 = 0.f, a7 = 0.f;
            for (int base = row; base < end; base += 64) {
                int cnt = min(64, end - base);
                bool valid = lane < cnt;
                int s = valid ? srcbuf[base + lane] : 0;
                float wt = valid ? __expf(lrelu(ssrc[s] + sdv)) : 0.f;
                lacc += wt;
                s_sh[w][lane] = s;
                w_sh[w][lane] = wt;
                // wave-private LDS; lockstep wave. All 64 s_sh/w_sh entries are
                // written each block-iter (0 for invalid), so reads below are safe.
                int cnt16 = (cnt + 15) & ~15;
                for (int j = 0; j < cnt16; j += 16) {
                    int e0 = j + g, e1 = j + 8 + g;
                    int sj0 = s_sh[w][e0], sj1 = s_sh[w][e1];
                    float wj0 = w_sh[w][e0], wj1 = w_sh[w][e1];
                    uint4 u0 = *(const uint4*)(zh + (size_t)sj0 * 64 + k * 8);
                    uint4 u1 = *(const uint4*)(zh + (size_t)sj1 * 64 + k * 8);
                    FMAMIX_LO(a0, u0.x, wj0); FMAMIX_HI(a1, u0.x, wj0);
                    FMAMIX_LO(a2, u0.y, wj0); FMAMIX_HI(a3, u0.y, wj0);
                    FMAMIX_LO(a4, u0.z, wj0); FMAMIX_HI(a5, u0.z, wj0);
                    FMAMIX_LO(a6, u0.w, wj0); FMAMIX_HI(a7, u0.w, wj0);
                    FMAMIX_LO(a0, u1.x, wj1); FMAMIX_HI(a1, u1.x, wj1);
                    FMAMIX_LO(a2, u1.y, wj1); FMAMIX_HI(a3, u1.y, wj1);
                    FMAMIX_LO(a4, u1.z, wj1); FMAMIX_HI(a5, u1.z, wj1);
                    FMAMIX_LO(a6, u1.w, wj1); FMAMIX_HI(a7, u1.w, wj1);
                }
            }
            // reduce over the 8 edge-groups (lane bits 3..5)
            #define GRED(a) { a += __shfl_xor(a, 8, 64); a += __shfl_xor(a, 16, 64); a += __shfl_xor(a, 32, 64); }
            GRED(a0) GRED(a1) GRED(a2) GRED(a3)
            GRED(a4) GRED(a5) GRED(a6) GRED(a7)
            #undef GRED
            float rl = 1.f / wrsum(lacc);
            m0 = fminf(m0, a0 * rl); m1 = fminf(m1, a1 * rl);
            m2 = fminf(m2, a2 * rl); m3 = fminf(m3, a3 * rl);
            m4 = fminf(m4, a4 * rl); m5 = fminf(m5, a5 * rl);
            m6 = fminf(m6, a6 * rl); m7 = fminf(m7, a7 * rl);
        }
    }
    if (g == 0) {                          // lanes 0..7: channels 8k..8k+7
        float* sp = &smc[w][k * 8];
        sp[0] = m0; sp[1] = m1; sp[2] = m2; sp[3] = m3;
        sp[4] = m4; sp[5] = m5; sp[6] = m6; sp[7] = m7;
    }
    __syncthreads();
    if (w == 0) {
        float v = fminf(fminf(smc[0][lane], smc[1][lane]),
                        fminf(smc[2][lane], smc[3][lane]));
        atomicMin(&minenc[lane], fenc(v));
    }
}

__global__ void decode_kernel(const unsigned* __restrict__ minenc, float* __restrict__ out) {
    int d = threadIdx.x;
    if (d < 64) out[d] = fdec(minenc[d]);
}

// ---------- launch ----------
extern "C" void kernel_launch(void* const* d_in, const int* in_sizes, int n_in,
                              void* d_out, int out_size, void* d_ws, size_t ws_size,
                              hipStream_t stream) {
    const float* x      = (const float*)d_in[0];
    const int*   ei     = (const int*)d_in[1];
    const float* W1     = (const float*)d_in[2];
    const float* a_src1 = (const float*)d_in[3];
    const float* a_dst1 = (const float*)d_in[4];
    const float* b1     = (const float*)d_in[5];
    const float* W2     = (const float*)d_in[6];
    const float* a_src2 = (const float*)d_in[7];
    const float* a_dst2 = (const float*)d_in[8];
    const float* b2     = (const float*)d_in[9];
    float* out = (float*)d_out;

    const int N = in_sizes[0] / 128;
    const int E = in_sizes[1] / 2;
    const int Etot = E + N;
    const int Epad = Etot + 64;
    const int M = N + 1;

    const int BB  = ((N - 1) >> 8) + 1;    // dst buckets (dst>>8), 196 for N=50000
    const int NBA = (Etot + 4095) / 4096;  // hist chunks, 208 for Etot=850000 (<=256)

    // workspace layout (4-byte words; N divisible by 4 keeps 16B alignment)
    float* ws = (float*)d_ws;
    ushort_t* h1b = (ushort_t*)ws;                     // N*256 f16 = N*128 words
    ushort_t* x2b = (ushort_t*)(ws + (size_t)N * 128); // N*256 f16
    ushort_t* zh  = (ushort_t*)(ws + (size_t)N * 256); // N*64 f16 (region N*64 words)
    ushort_t* W1s = (ushort_t*)(ws + (size_t)N * 320); // 32768 f16 = 16384 words
    ushort_t* W2s = (ushort_t*)(ws + (size_t)N * 320 + 16384); // 16384 f16 = 8192 words
    float* ssrc1  = ws + (size_t)N * 320 + 24576;      // 4N (16B aligned)
    float* sdst1  = ssrc1 + (size_t)N * 4;             // 4N
    float* ssrc2  = sdst1 + (size_t)N * 4;             // N
    float* sdst2  = ssrc2 + N;                         // N
    float* va     = sdst2 + N;                         // 256
    float* vb     = va + 256;                          // 256
    int*   bh     = (int*)(vb + 256);                  // BB*NBA (<= M = N+1 words)
    int*   rowptr = bh + M;                            // N+1
    int*   gtot   = rowptr + M;                        // 256
    int*   bstart = gtot + 256;                        // 256 (BB+1 used)
    int*   srcbuf = bstart + 256;                      // Epad
    unsigned* minenc = (unsigned*)(srcbuf + Epad);     // 64

    int nb16 = (N + 15) / 16;
    int nb32 = (N + 31) / 32;
    int nb4 = (N + 3) / 4;
    int nbz = 2048;                        // grid-stride; 8 blocks/CU

    pre_kernel<<<193, 256, 0, stream>>>(W1, W2, a_src2, a_dst2, W1s, W2s, va, vb,
                                        minenc, gtot);
    front_kernel<<<nb16 + NBA, 256, 0, stream>>>(x, W1s, a_src1, a_dst1, h1b, ssrc1, sdst1,
                                                 ei, bh, gtot, N, E, Etot, nb16, NBA, BB);
    scan2_kernel<<<BB + 1, 256, 0, stream>>>(bh, gtot, bstart, NBA, BB);
    scat_kernel<<<NBA, 256, 0, stream>>>(ei, bh, bstart, srcbuf, E, Etot, NBA, BB);
    csr_kernel<<<BB, 256, 0, stream>>>(bstart, srcbuf, rowptr, N);

    agg1_kernel<<<nb4, 256, 0, stream>>>(rowptr, srcbuf, ssrc1, sdst1, h1b, b1,
                                         va, vb, x2b, ssrc2, sdst2, N);
    gemmz_kernel<<<nb32, 256, 0, stream>>>(x2b, W2s, b2, zh, N);
    aggz_kernel<<<nbz, 256, 0, stream>>>(rowptr, srcbuf, ssrc2, sdst2, zh, minenc, N);
    decode_kernel<<<1, 64, 0, stream>>>(minenc, out);
}

// Round 11
// 267.056 us; speedup vs baseline: 1.4691x; 1.0031x over previous
//
#include <hip/hip_runtime.h>
#include <math.h>

typedef unsigned short ushort_t;
typedef __attribute__((ext_vector_type(8))) _Float16 f16x8;
typedef __attribute__((ext_vector_type(4))) float f32x4;

// ---------- helpers ----------

__device__ inline unsigned fenc(float f) {
    unsigned u = __float_as_uint(f);
    return (u & 0x80000000u) ? ~u : (u | 0x80000000u);
}
__device__ inline float fdec(unsigned u) {
    return __uint_as_float((u & 0x80000000u) ? (u ^ 0x80000000u) : ~u);
}

__device__ inline float wrsum(float v) {
    #pragma unroll
    for (int m = 32; m; m >>= 1) v += __shfl_xor(v, m, 64);
    return v;
}
__device__ inline float lrelu(float x) { return x > 0.f ? x : 0.2f * x; }

__device__ inline ushort_t f2h(float f) {
    _Float16 h = (_Float16)f;              // RNE
    union { _Float16 h; ushort_t u; } cv;
    cv.h = h;
    return cv.u;
}

// acc += f16(lo half of pk) * w   /   acc += f16(hi half of pk) * w
#define FMAMIX_LO(acc, pk, w) \
    asm("v_fma_mix_f32 %0, %1, %2, %0 op_sel:[0,0,0] op_sel_hi:[1,0,0]" \
        : "+v"(acc) : "v"(pk), "v"(w))
#define FMAMIX_HI(acc, pk, w) \
    asm("v_fma_mix_f32 %0, %1, %2, %0 op_sel:[1,0,0] op_sel_hi:[1,0,0]" \
        : "+v"(acc) : "v"(pk), "v"(w))

// ---------- pre kernel: W swizzles + vab + inits ----------
__global__ __launch_bounds__(256) void pre_kernel(const float* __restrict__ W1,
                                                  const float* __restrict__ W2,
                                                  const float* __restrict__ a_src2,
                                                  const float* __restrict__ a_dst2,
                                                  ushort_t* __restrict__ W1s,
                                                  ushort_t* __restrict__ W2s,
                                                  float* __restrict__ va,
                                                  float* __restrict__ vb,
                                                  unsigned* __restrict__ minenc,
                                                  int* __restrict__ gtot) {
    int bid = blockIdx.x;
    int tid = threadIdx.x;
    if (bid < 128) {                       // W1 swizzle: 32768 elems
        int idx = bid * 256 + tid;
        int j = idx & 7;
        int lane = (idx >> 3) & 63;
        int ct = (idx >> 9) & 15;
        int kc = (idx >> 13) & 3;
        int k = kc * 32 + (lane >> 4) * 8 + j;
        int c = ct * 16 + (lane & 15);
        W1s[idx] = f2h(W1[k * 256 + c]);
    } else if (bid < 192) {                // W2 swizzle: 16384 elems
        int idx = (bid - 128) * 256 + tid;
        int j = idx & 7;
        int lane = (idx >> 3) & 63;
        int ct = (idx >> 9) & 3;
        int kc = idx >> 11;
        int k = kc * 32 + (lane >> 4) * 8 + j;
        int c = ct * 16 + (lane & 15);
        W2s[idx] = f2h(W2[k * 64 + c]);
    } else {                               // vab + minenc/gtot init
        int k = tid;
        float sa = 0.f, sb = 0.f;
        #pragma unroll 8
        for (int c = 0; c < 64; c++) {
            float w = W2[k * 64 + c];
            sa += w * a_src2[c];
            sb += w * a_dst2[c];
        }
        va[k] = sa;
        vb[k] = sb;
        if (tid < 64) minenc[tid] = 0xFFFFFFFFu;
        gtot[tid] = 0;
    }
}

// ---------- front kernel: MFMA gemm1 (f16) + scores1, with hist blocks appended ----------
__global__ __launch_bounds__(256) void front_kernel(const float* __restrict__ x,
                                                    const ushort_t* __restrict__ W1s,
                                                    const float* __restrict__ a_src,
                                                    const float* __restrict__ a_dst,
                                                    ushort_t* __restrict__ h1b,
                                                    float* __restrict__ ssrc,
                                                    float* __restrict__ sdst,
                                                    const int* __restrict__ ei,
                                                    int* __restrict__ bh,
                                                    int* __restrict__ gtot,
                                                    int N, int E, int Etot,
                                                    int nb16, int NBA, int BB) {
    __shared__ float ss[16 * 257];         // aliased: x staging first, D-tile after
    __shared__ float ps[256];
    int bid = blockIdx.x;
    int tid = threadIdx.x;

    if (bid >= nb16) {                     // ---- hist ----
        int* h = (int*)ps;
        int blk = bid - nb16;
        h[tid] = 0;
        __syncthreads();
        int i0 = blk * 4096 + tid;
        #pragma unroll
        for (int e = 0; e < 16; e++) {
            int i = i0 + e * 256;
            if (i < Etot) {
                int d = (i < E) ? ei[E + i] : (i - E);
                atomicAdd(&h[d >> 8], 1);
            }
        }
        __syncthreads();
        if (tid < BB) {
            bh[tid * NBA + blk] = h[tid];
            atomicAdd(&gtot[tid], h[tid]);
        }
        return;
    }

    // ---- stage x tile into LDS (coalesced; rows padded to 33 float4 = 132 floats) ----
    int base = bid * 16;
    {
        const float4* xv = (const float4*)(x + (size_t)base * 128);
        float4* xs4 = (float4*)ss;
        #pragma unroll
        for (int i = tid; i < 512; i += 256) {
            int row = i >> 5;              // 32 float4 per row
            float4 v = (base + row < N) ? xv[i] : make_float4(0.f, 0.f, 0.f, 0.f);
            xs4[row * 33 + (i & 31)] = v;
        }
    }
    __syncthreads();

    // ---- build A-fragments from LDS ----
    int lane = tid & 63, wv = tid >> 6;
    int m = lane & 15, q = lane >> 4;
    f16x8 afrag[4];
    #pragma unroll
    for (int kc = 0; kc < 4; kc++) {
        const float* xp = ss + m * 132 + kc * 32 + q * 8;
        float4 xa = *(const float4*)xp;
        float4 xb = *(const float4*)(xp + 4);
        f16x8 af;
        af[0] = (_Float16)xa.x; af[1] = (_Float16)xa.y;
        af[2] = (_Float16)xa.z; af[3] = (_Float16)xa.w;
        af[4] = (_Float16)xb.x; af[5] = (_Float16)xb.y;
        af[6] = (_Float16)xb.z; af[7] = (_Float16)xb.w;
        afrag[kc] = af;
    }
    __syncthreads();                       // xs dead; ss reused for D-tiles

    #pragma unroll
    for (int t = 0; t < 4; t++) {
        int ct = wv * 4 + t;
        f32x4 acc = {0.f, 0.f, 0.f, 0.f};
        #pragma unroll
        for (int kc = 0; kc < 4; kc++) {
            f16x8 bfrag = *(const f16x8*)(W1s + (((size_t)(kc * 16 + ct) * 64 + lane) << 3));
            acc = __builtin_amdgcn_mfma_f32_16x16x32_f16(afrag[kc], bfrag, acc, 0, 0, 0);
        }
        #pragma unroll
        for (int reg = 0; reg < 4; reg++) {
            ss[(q * 4 + reg) * 257 + ct * 16 + m] = acc[reg];
        }
    }
    __syncthreads();

    // ---- dense h1b writes: CHANNEL-CONTIGUOUS rows (h1b[n][c], c=0..255) ----
    // thread (j, dd) packs channels dd*4 .. dd*4+3 into one uint2.
    int dd = tid & 63, jj = tid >> 6;
    #pragma unroll
    for (int t2 = 0; t2 < 4; t2++) {
        int j = jj + t2 * 4;
        int n = base + j;
        if (n < N) {
            const float* row = ss + j * 257 + dd * 4;
            unsigned p0 = (unsigned)f2h(row[0]) | ((unsigned)f2h(row[1]) << 16);
            unsigned p1 = (unsigned)f2h(row[2]) | ((unsigned)f2h(row[3]) << 16);
            *(uint2*)(h1b + (size_t)n * 256 + dd * 4) = make_uint2(p0, p1);
        }
    }
    // ---- scores via partial sums (hh2-rotated) ----
    int j = tid & 15, hh2 = (tid >> 4) & 3, which = (tid >> 6) & 1, half = tid >> 7;
    const float* av = which ? a_dst : a_src;
    int cbase = hh2 * 64 + half * 32;
    float sum = 0.f;
    #pragma unroll
    for (int i = 0; i < 32; i++) {
        int ii = (i + 8 * hh2) & 31;
        sum += ss[j * 257 + cbase + ii] * av[cbase + ii];
    }
    ps[tid] = sum;
    __syncthreads();
    if (half == 0) {
        float tot = sum + ps[tid + 128];
        int n = base + j;
        if (n < N) (which ? sdst : ssrc)[n * 4 + hh2] = tot;
    }
}

// ---------- scan2: blocks 0..BB-1 scan bh rows over chunks; block BB scans gtot ----------
__global__ __launch_bounds__(256) void scan2_kernel(int* __restrict__ bh,
                                                    const int* __restrict__ gtot,
                                                    int* __restrict__ bstart,
                                                    int NBA, int BB) {
    __shared__ int sm[256];
    int b = blockIdx.x, t = threadIdx.x;
    if (b < BB) {                          // per-bucket exclusive scan over blocks
        int v = (t < NBA) ? bh[b * NBA + t] : 0;
        sm[t] = v;
        __syncthreads();
        for (int o = 1; o < 256; o <<= 1) {
            int a = (t >= o) ? sm[t - o] : 0;
            __syncthreads();
            sm[t] += a;
            __syncthreads();
        }
        if (t < NBA) bh[b * NBA + t] = sm[t] - v;
    } else {                               // bucket-level exclusive scan
        int v = (t < BB) ? gtot[t] : 0;
        sm[t] = v;
        __syncthreads();
        for (int o = 1; o < 256; o <<= 1) {
            int a = (t >= o) ? sm[t - o] : 0;
            __syncthreads();
            sm[t] += a;
            __syncthreads();
        }
        if (t < BB) bstart[t] = sm[t] - v;
        if (t == BB - 1) bstart[BB] = sm[t];
    }
}

// ---------- scat: recompute local ranks, block-local counting sort, run-coalesced writes ----------
__global__ __launch_bounds__(256) void scat_kernel(const int* __restrict__ ei,
                                                   const int* __restrict__ bh,
                                                   const int* __restrict__ bstart,
                                                   int* __restrict__ srcbuf,
                                                   int E, int Etot, int NBA, int BB) {
    __shared__ int h[256];
    __shared__ int loff[256];
    __shared__ int gb[256];
    __shared__ int su[4096];
    __shared__ int sp[4096];
    int t = threadIdx.x, blk = blockIdx.x;
    h[t] = 0;
    __syncthreads();
    int i0 = blk * 4096;
    int blkcnt = min(4096, Etot - i0);

    // pass 1: (bucket, rank) per edge via LDS atomics (counts match hist deterministically)
    int rb[16];
    #pragma unroll
    for (int e = 0; e < 16; e++) {
        int i = i0 + e * 256 + t;
        rb[e] = -1;
        if (i < Etot) {
            int d = (i < E) ? ei[E + i] : (i - E);
            int b = d >> 8;
            int r = atomicAdd(&h[b], 1);
            rb[e] = (b << 12) | r;         // r < 4096
        }
    }
    __syncthreads();

    // local exclusive offsets + global bases
    loff[t] = h[t];
    gb[t] = (t < BB) ? (bstart[t] + bh[t * NBA + blk]) : 0;
    __syncthreads();
    for (int o = 1; o < 256; o <<= 1) {
        int a = (t >= o) ? loff[t - o] : 0;
        __syncthreads();
        loff[t] += a;
        __syncthreads();
    }

    // pass 2: place payload + global position at locally-sorted slot
    #pragma unroll
    for (int e = 0; e < 16; e++) {
        int i = i0 + e * 256 + t;
        if (i < Etot) {
            int s = (i < E) ? ei[i] : (i - E);
            int d = (i < E) ? ei[E + i] : (i - E);
            int b = rb[e] >> 12;
            int r = rb[e] & 0xFFF;
            int slot = loff[b] - h[b] + r;
            su[slot] = s | ((d & 255) << 16);
            sp[slot] = gb[b] + r;
        }
    }
    __syncthreads();

    // pass 3: linear read, mostly-contiguous writes (runs of ~21 per bucket)
    for (int k = t; k < blkcnt; k += 256) {
        srcbuf[sp[k]] = su[k];
    }
}

// ---------- stage 4: per-bucket CSR finalize (LDS-only atomics) ----------
__global__ __launch_bounds__(256) void csr_kernel(const int* __restrict__ bstart,
                                                  int* __restrict__ srcbuf,
                                                  int* __restrict__ rowptr, int N) {
    __shared__ int eb[8192];
    __shared__ unsigned short rr[8192];
    __shared__ int h[256];
    __shared__ int off[256];
    int b = blockIdx.x, t = threadIdx.x;
    int s0 = bstart[b];
    int cnt = bstart[b + 1] - s0;
    if (cnt > 8192) cnt = 8192;            // impossible (mean 4352, sigma 64); safety
    h[t] = 0;
    __syncthreads();
    for (int j = t; j < cnt; j += 256) {
        int u = srcbuf[s0 + j];
        eb[j] = u;
        rr[j] = (unsigned short)atomicAdd(&h[u >> 16], 1);
    }
    __syncthreads();
    off[t] = h[t];
    __syncthreads();
    for (int o = 1; o < 256; o <<= 1) {
        int a = (t >= o) ? off[t - o] : 0;
        __syncthreads();
        off[t] += a;
        __syncthreads();
    }
    int excl = off[t] - h[t];
    int d = b * 256 + t;
    if (d <= N) rowptr[d] = s0 + excl;
    __syncthreads();
    h[t] = excl;                           // reuse h as exclusive bin offsets
    __syncthreads();
    for (int j = t; j < cnt; j += 256) {
        int u = eb[j];
        srcbuf[s0 + h[u >> 16] + rr[j]] = u & 0xFFFF;
    }
}

// ---------- layer-1 aggregation: half-wave uint4 gathers, 4-deep MLP,
// denominator folded into gather loop (no wrsum chains) ----------
__global__ __launch_bounds__(256) void agg1_kernel(const int* __restrict__ rowptr,
                                                   const int* __restrict__ srcbuf,
                                                   const float* __restrict__ ssrc,
                                                   const float* __restrict__ sdst,
                                                   const ushort_t* __restrict__ h1b,
                                                   const float* __restrict__ b1,
                                                   const float* __restrict__ va,
                                                   const float* __restrict__ vb,
                                                   ushort_t* __restrict__ x2b,
                                                   float* __restrict__ ssrc2,
                                                   float* __restrict__ sdst2, int N) {
    __shared__ int    s_sh[4][64];
    __shared__ float4 w_sh[4][64];
    int lane = threadIdx.x & 63, w = threadIdx.x >> 6;
    int li = lane & 31, half = lane >> 5;
    int hh = li >> 3;                      // head owning channels [8*li, 8*li+8)
    int d = blockIdx.x * 4 + w;
    if (d >= N) return;
    int row = rowptr[d], end = rowptr[d + 1];
    float4 sd = *(const float4*)(sdst + d * 4);
    float aW = 0.f;                        // per-head denominator (this half's edges)
    float a0 = 0.f, a1 = 0.f, a2 = 0.f, a3 = 0.f;
    float a4 = 0.f, a5 = 0.f, a6 = 0.f, a7 = 0.f;

    for (int base = row; base < end; base += 64) {
        int cnt = min(64, end - base);
        bool valid = lane < cnt;
        int s = valid ? srcbuf[base + lane] : 0;
        float4 ssv = *(const float4*)(ssrc + s * 4);
        float w0 = valid ? __expf(lrelu(ssv.x + sd.x)) : 0.f;
        float w1 = valid ? __expf(lrelu(ssv.y + sd.y)) : 0.f;
        float w2 = valid ? __expf(lrelu(ssv.z + sd.z)) : 0.f;
        float w3 = valid ? __expf(lrelu(ssv.w + sd.w)) : 0.f;
        s_sh[w][lane] = s;
        w_sh[w][lane] = make_float4(w0, w1, w2, w3);
        // wave-private LDS; lockstep wave, no barrier needed
        // 4 gathers in flight per half-wave (8 edges per iteration)
        int cnt8 = (cnt + 7) & ~7;
        for (int j = 0; j < cnt8; j += 8) {
            int ea = j + half, eb = j + 2 + half, ec = j + 4 + half, ed = j + 6 + half;
            int sa_ = s_sh[w][ea], sb_ = s_sh[w][eb], sc_ = s_sh[w][ec], sd_ = s_sh[w][ed];
            float wa = ((const float*)(w_sh[w] + ea))[hh];
            float wb = ((const float*)(w_sh[w] + eb))[hh];
            float wc = ((const float*)(w_sh[w] + ec))[hh];
            float wd = ((const float*)(w_sh[w] + ed))[hh];
            uint4 ua = *(const uint4*)(h1b + (size_t)sa_ * 256 + li * 8);
            uint4 ub = *(const uint4*)(h1b + (size_t)sb_ * 256 + li * 8);
            uint4 uc = *(const uint4*)(h1b + (size_t)sc_ * 256 + li * 8);
            uint4 ud = *(const uint4*)(h1b + (size_t)sd_ * 256 + li * 8);
            aW += (wa + wb) + (wc + wd);   // invalid slots carry w = 0
            FMAMIX_LO(a0, ua.x, wa); FMAMIX_HI(a1, ua.x, wa);
            FMAMIX_LO(a2, ua.y, wa); FMAMIX_HI(a3, ua.y, wa);
            FMAMIX_LO(a4, ua.z, wa); FMAMIX_HI(a5, ua.z, wa);
            FMAMIX_LO(a6, ua.w, wa); FMAMIX_HI(a7, ua.w, wa);
            FMAMIX_LO(a0, ub.x, wb); FMAMIX_HI(a1, ub.x, wb);
            FMAMIX_LO(a2, ub.y, wb); FMAMIX_HI(a3, ub.y, wb);
            FMAMIX_LO(a4, ub.z, wb); FMAMIX_HI(a5, ub.z, wb);
            FMAMIX_LO(a6, ub.w, wb); FMAMIX_HI(a7, ub.w, wb);
            FMAMIX_LO(a0, uc.x, wc); FMAMIX_HI(a1, uc.x, wc);
            FMAMIX_LO(a2, uc.y, wc); FMAMIX_HI(a3, uc.y, wc);
            FMAMIX_LO(a4, uc.z, wc); FMAMIX_HI(a5, uc.z, wc);
            FMAMIX_LO(a6, uc.w, wc); FMAMIX_HI(a7, uc.w, wc);
            FMAMIX_LO(a0, ud.x, wd); FMAMIX_HI(a1, ud.x, wd);
            FMAMIX_LO(a2, ud.y, wd); FMAMIX_HI(a3, ud.y, wd);
            FMAMIX_LO(a4, ud.z, wd); FMAMIX_HI(a5, ud.z, wd);
            FMAMIX_LO(a6, ud.w, wd); FMAMIX_HI(a7, ud.w, wd);
        }
    }
    // combine halves (lanes li and li+32 hold the two edge-subsets of same channels)
    a0 += __shfl_xor(a0, 32, 64); a1 += __shfl_xor(a1, 32, 64);
    a2 += __shfl_xor(a2, 32, 64); a3 += __shfl_xor(a3, 32, 64);
    a4 += __shfl_xor(a4, 32, 64); a5 += __shfl_xor(a5, 32, 64);
    a6 += __shfl_xor(a6, 32, 64); a7 += __shfl_xor(a7, 32, 64);
    float lh = aW + __shfl_xor(aW, 32, 64);  // head-specific denominator (hh matches across halves)
    float rl = 1.f / lh;
    int c8 = li * 8;
    float4 b1a = *(const float4*)(b1 + c8);
    float4 b1b = *(const float4*)(b1 + c8 + 4);
    float v0 = a0 * rl + b1a.x, v1 = a1 * rl + b1a.y;
    float v2 = a2 * rl + b1a.z, v3 = a3 * rl + b1a.w;
    float v4 = a4 * rl + b1b.x, v5 = a5 * rl + b1b.y;
    float v6 = a6 * rl + b1b.z, v7 = a7 * rl + b1b.w;
    v0 = v0 > 0.f ? v0 : __expf(v0) - 1.f;
    v1 = v1 > 0.f ? v1 : __expf(v1) - 1.f;
    v2 = v2 > 0.f ? v2 : __expf(v2) - 1.f;
    v3 = v3 > 0.f ? v3 : __expf(v3) - 1.f;
    v4 = v4 > 0.f ? v4 : __expf(v4) - 1.f;
    v5 = v5 > 0.f ? v5 : __expf(v5) - 1.f;
    v6 = v6 > 0.f ? v6 : __expf(v6) - 1.f;
    v7 = v7 > 0.f ? v7 : __expf(v7) - 1.f;
    if (half == 0) {
        unsigned p0 = (unsigned)f2h(v0) | ((unsigned)f2h(v1) << 16);
        unsigned p1 = (unsigned)f2h(v2) | ((unsigned)f2h(v3) << 16);
        unsigned p2 = (unsigned)f2h(v4) | ((unsigned)f2h(v5) << 16);
        unsigned p3 = (unsigned)f2h(v6) | ((unsigned)f2h(v7) << 16);
        *(uint4*)(x2b + (size_t)d * 256 + c8) = make_uint4(p0, p1, p2, p3);
    }
    float4 vaa = *(const float4*)(va + c8), vab = *(const float4*)(va + c8 + 4);
    float4 vba = *(const float4*)(vb + c8), vbb = *(const float4*)(vb + c8 + 4);
    float sa = v0 * vaa.x + v1 * vaa.y + v2 * vaa.z + v3 * vaa.w
             + v4 * vab.x + v5 * vab.y + v6 * vab.z + v7 * vab.w;
    float sb = v0 * vba.x + v1 * vba.y + v2 * vba.z + v3 * vba.w
             + v4 * vbb.x + v5 * vbb.y + v6 * vbb.z + v7 * vbb.w;
    sa = wrsum(sa) * 0.5f;                 // values duplicated across halves
    sb = wrsum(sb) * 0.5f;
    if (lane == 0) { ssrc2[d] = sa; sdst2[d] = sb; }
}

// ---------- gemmz via MFMA (f16): z = x2b @ W2 + b2, stored f16 (N x 64) ----------
__global__ __launch_bounds__(256) void gemmz_kernel(const ushort_t* __restrict__ x2b,
                                                    const ushort_t* __restrict__ W2s,
                                                    const float* __restrict__ b2,
                                                    ushort_t* __restrict__ zh, int N) {
    int base = blockIdx.x * 32;
    int tid = threadIdx.x;
    int lane = tid & 63, wv = tid >> 6;
    int m = lane & 15, q = lane >> 4;
    int c = wv * 16 + m;
    float bc = b2[c];

    #pragma unroll
    for (int h = 0; h < 2; h++) {
        int rbase = base + h * 16;
        bool rowok = (rbase + m) < N;
        const ushort_t* xrow = x2b + (size_t)(rbase + m) * 256;
        f32x4 acc = {0.f, 0.f, 0.f, 0.f};
        #pragma unroll
        for (int kc = 0; kc < 8; kc++) {
            f16x8 af = {0, 0, 0, 0, 0, 0, 0, 0};
            if (rowok) af = *(const f16x8*)(xrow + kc * 32 + q * 8);
            f16x8 bf = *(const f16x8*)(W2s + (((size_t)(kc * 4 + wv) * 64 + lane) << 3));
            acc = __builtin_amdgcn_mfma_f32_16x16x32_f16(af, bf, acc, 0, 0, 0);
        }
        #pragma unroll
        for (int reg = 0; reg < 4; reg++) {
            int n = rbase + q * 4 + reg;
            if (n < N) zh[(size_t)n * 64 + c] = f2h(acc[reg] + bc);
        }
    }
}

// ---------- layer-2 aggregation: 8-lane-group uint4 gathers (j+=8, measured-best),
// denominator folded into gather loop ----------
__global__ __launch_bounds__(256) void aggz_kernel(const int* __restrict__ rowptr,
                                                   const int* __restrict__ srcbuf,
                                                   const float* __restrict__ ssrc,
                                                   const float* __restrict__ sdst,
                                                   const ushort_t* __restrict__ zh,
                                                   unsigned* __restrict__ minenc, int N) {
    __shared__ int   s_sh[4][64];
    __shared__ float w_sh[4][64];
    __shared__ float smc[4][64];
    int lane = threadIdx.x & 63, w = threadIdx.x >> 6;
    int k = lane & 7, g = lane >> 3;
    float m0 = INFINITY, m1 = INFINITY, m2 = INFINITY, m3 = INFINITY;
    float m4 = INFINITY, m5 = INFINITY, m6 = INFINITY, m7 = INFINITY;

    for (int d0 = blockIdx.x * 4; d0 < N; d0 += gridDim.x * 4) {
        int d = d0 + w;
        if (d < N) {
            int row = rowptr[d], end = rowptr[d + 1];
            float sdv = sdst[d];
            float aW = 0.f;                // this group's share of the denominator
            float a0 = 0.f, a1 = 0.f, a2 = 0.f, a3 = 0.f;
            float a4 = 0.f, a5 = 0.f, a6 = 0.f, a7 = 0.f;
            for (int base = row; base < end; base += 64) {
                int cnt = min(64, end - base);
                bool valid = lane < cnt;
                int s = valid ? srcbuf[base + lane] : 0;
                float wt = valid ? __expf(lrelu(ssrc[s] + sdv)) : 0.f;
                s_sh[w][lane] = s;
                w_sh[w][lane] = wt;
                // wave-private LDS; lockstep wave. All 64 s_sh/w_sh entries are
                // written each block-iter (0 for invalid), so reads below are safe.
                int cnt8 = (cnt + 7) & ~7;
                for (int j = 0; j < cnt8; j += 8) {
                    int e = j + g;
                    int sj = s_sh[w][e];
                    float wj = w_sh[w][e];
                    uint4 u = *(const uint4*)(zh + (size_t)sj * 64 + k * 8);
                    aW += wj;              // invalid slots carry w = 0
                    FMAMIX_LO(a0, u.x, wj); FMAMIX_HI(a1, u.x, wj);
                    FMAMIX_LO(a2, u.y, wj); FMAMIX_HI(a3, u.y, wj);
                    FMAMIX_LO(a4, u.z, wj); FMAMIX_HI(a5, u.z, wj);
                    FMAMIX_LO(a6, u.w, wj); FMAMIX_HI(a7, u.w, wj);
                }
            }
            // reduce over the 8 edge-groups (lane bits 3..5)
            #define GRED(a) { a += __shfl_xor(a, 8, 64); a += __shfl_xor(a, 16, 64); a += __shfl_xor(a, 32, 64); }
            GRED(a0) GRED(a1) GRED(a2) GRED(a3)
            GRED(a4) GRED(a5) GRED(a6) GRED(a7)
            GRED(aW)
            #undef GRED
            float rl = 1.f / aW;
            m0 = fminf(m0, a0 * rl); m1 = fminf(m1, a1 * rl);
            m2 = fminf(m2, a2 * rl); m3 = fminf(m3, a3 * rl);
            m4 = fminf(m4, a4 * rl); m5 = fminf(m5, a5 * rl);
            m6 = fminf(m6, a6 * rl); m7 = fminf(m7, a7 * rl);
        }
    }
    if (g == 0) {                          // lanes 0..7: channels 8k..8k+7
        float* sp = &smc[w][k * 8];
        sp[0] = m0; sp[1] = m1; sp[2] = m2; sp[3] = m3;
        sp[4] = m4; sp[5] = m5; sp[6] = m6; sp[7] = m7;
    }
    __syncthreads();
    if (w == 0) {
        float v = fminf(fminf(smc[0][lane], smc[1][lane]),
                        fminf(smc[2][lane], smc[3][lane]));
        atomicMin(&minenc[lane], fenc(v));
    }
}

__global__ void decode_kernel(const unsigned* __restrict__ minenc, float* __restrict__ out) {
    int d = threadIdx.x;
    if (d < 64) out[d] = fdec(minenc[d]);
}

// ---------- launch ----------
extern "C" void kernel_launch(void* const* d_in, const int* in_sizes, int n_in,
                              void* d_out, int out_size, void* d_ws, size_t ws_size,
                              hipStream_t stream) {
    const float* x      = (const float*)d_in[0];
    const int*   ei     = (const int*)d_in[1];
    const float* W1     = (const float*)d_in[2];
    const float* a_src1 = (const float*)d_in[3];
    const float* a_dst1 = (const float*)d_in[4];
    const float* b1     = (const float*)d_in[5];
    const float* W2     = (const float*)d_in[6];
    const float* a_src2 = (const float*)d_in[7];
    const float* a_dst2 = (const float*)d_in[8];
    const float* b2     = (const float*)d_in[9];
    float* out = (float*)d_out;

    const int N = in_sizes[0] / 128;
    const int E = in_sizes[1] / 2;
    const int Etot = E + N;
    const int Epad = Etot + 64;
    const int M = N + 1;

    const int BB  = ((N - 1) >> 8) + 1;    // dst buckets (dst>>8), 196 for N=50000
    const int NBA = (Etot + 4095) / 4096;  // hist chunks, 208 for Etot=850000 (<=256)

    // workspace layout (4-byte words; N divisible by 4 keeps 16B alignment)
    float* ws = (float*)d_ws;
    ushort_t* h1b = (ushort_t*)ws;                     // N*256 f16 = N*128 words
    ushort_t* x2b = (ushort_t*)(ws + (size_t)N * 128); // N*256 f16
    ushort_t* zh  = (ushort_t*)(ws + (size_t)N * 256); // N*64 f16 (region N*64 words)
    ushort_t* W1s = (ushort_t*)(ws + (size_t)N * 320); // 32768 f16 = 16384 words
    ushort_t* W2s = (ushort_t*)(ws + (size_t)N * 320 + 16384); // 16384 f16 = 8192 words
    float* ssrc1  = ws + (size_t)N * 320 + 24576;      // 4N (16B aligned)
    float* sdst1  = ssrc1 + (size_t)N * 4;             // 4N
    float* ssrc2  = sdst1 + (size_t)N * 4;             // N
    float* sdst2  = ssrc2 + N;                         // N
    float* va     = sdst2 + N;                         // 256
    float* vb     = va + 256;                          // 256
    int*   bh     = (int*)(vb + 256);                  // BB*NBA (<= M = N+1 words)
    int*   rowptr = bh + M;                            // N+1
    int*   gtot   = rowptr + M;                        // 256
    int*   bstart = gtot + 256;                        // 256 (BB+1 used)
    int*   srcbuf = bstart + 256;                      // Epad
    unsigned* minenc = (unsigned*)(srcbuf + Epad);     // 64

    int nb16 = (N + 15) / 16;
    int nb32 = (N + 31) / 32;
    int nb4 = (N + 3) / 4;
    int nbz = 2048;                        // grid-stride; 8 blocks/CU

    pre_kernel<<<193, 256, 0, stream>>>(W1, W2, a_src2, a_dst2, W1s, W2s, va, vb,
                                        minenc, gtot);
    front_kernel<<<nb16 + NBA, 256, 0, stream>>>(x, W1s, a_src1, a_dst1, h1b, ssrc1, sdst1,
                                                 ei, bh, gtot, N, E, Etot, nb16, NBA, BB);
    scan2_kernel<<<BB + 1, 256, 0, stream>>>(bh, gtot, bstart, NBA, BB);
    scat_kernel<<<NBA, 256, 0, stream>>>(ei, bh, bstart, srcbuf, E, Etot, NBA, BB);
    csr_kernel<<<BB, 256, 0, stream>>>(bstart, srcbuf, rowptr, N);

    agg1_kernel<<<nb4, 256, 0, stream>>>(rowptr, srcbuf, ssrc1, sdst1, h1b, b1,
                                         va, vb, x2b, ssrc2, sdst2, N);
    gemmz_kernel<<<nb32, 256, 0, stream>>>(x2b, W2s, b2, zh, N);
    aggz_kernel<<<nbz, 256, 0, stream>>>(rowptr, srcbuf, ssrc2, sdst2, zh, minenc, N);
    decode_kernel<<<1, 64, 0, stream>>>(minenc, out);
}